// Round 6
// baseline (394.849 us; speedup 1.0000x reference)
//
#include <hip/hip_runtime.h>

#define G 250
#define GG 62500
#define NB 8
#define HFEAT 2000000
#define W1STRIDE 2000064
#define NCH 7813          // ceil(2,000,000 / 256)
#define SPAN 16           // chunks per block (contiguous span, 16 KB/row)

// ---------------- rasterize ----------------
__global__ void k_raster(const float* __restrict__ lidar, float* __restrict__ img) {
    int idx = blockIdx.x * blockDim.x + threadIdx.x;
    if (idx >= NB * 360 * 1000) return;
    int k = idx % 1000;
    int ba = idx / 1000;
    int a = ba % 360;
    int b = ba / 360;
    float r = lidar[ba];
    if (!(r > 0.0f && r < 1.0f)) return;
    float tmr = __fsub_rn(2.0f, r);
    int n = (int)floorf(__fmul_rn(tmr, 500.0f)) + 1;
    if (k >= n) return;
    float denom = (float)(n - 1);
    const float delta = 6.2831855f / 359.0f;      // fp32, matches jnp.linspace step
    float angle = __fmul_rn((float)a, delta);
    float mag = __fadd_rn(r, __fdiv_rn(__fmul_rn((float)k, tmr), denom));
    float c = cosf(angle);
    float s = sinf(angle);
    float px = __fadd_rn(125.0f, __fmul_rn(__fmul_rn(mag, c), 100.0f));
    float py = __fadd_rn(125.0f, __fmul_rn(__fmul_rn(mag, s), 100.0f));
    int xg = (int)px;   // trunc toward zero
    int yg = (int)py;
    if (xg >= 0 && xg < G && yg >= 0 && yg < G)
        img[b * GG + yg * G + xg] = 1.0f;
}

// ---------------- fused conv1(1->16)+conv2(16->32) ----------------
__global__ __launch_bounds__(256) void k_conv12(const float* __restrict__ img,
                                                const float* __restrict__ w1,
                                                const float* __restrict__ b1,
                                                const float* __restrict__ w2,
                                                const float* __restrict__ b2,
                                                float* __restrict__ h) {
    __shared__ float s_img[20][37];
    __shared__ float s_c1[16][18][35];
    __shared__ float s_w2[4608];
    __shared__ float s_w1[144];
    __shared__ float s_b1[16];
    int t = threadIdx.x;
    int bx = blockIdx.x, by = blockIdx.y, b = blockIdx.z;
    for (int i = t; i < 4608; i += 256) s_w2[i] = w2[i];
    if (t < 144) s_w1[t] = w1[t];
    if (t < 16) s_b1[t] = b1[t];
    int x0 = bx * 32 - 1, y0 = by * 16 - 1;   // c1-tile origin
    for (int i = t; i < 20 * 36; i += 256) {
        int r = i / 36, c = i - r * 36;
        int gy = y0 - 1 + r, gx = x0 - 1 + c;
        float v = 0.0f;
        if (gy >= 0 && gy < G && gx >= 0 && gx < G) v = img[b * GG + gy * G + gx];
        s_img[r][c] = v;
    }
    __syncthreads();
    for (int i = t; i < 612; i += 256) {
        int yy = i / 34, xx = i - yy * 34;
        int gy = y0 + yy, gx = x0 + xx;
        bool inb = (gy >= 0 && gy < G && gx >= 0 && gx < G);
        float iv[9];
#pragma unroll
        for (int dy = 0; dy < 3; ++dy)
#pragma unroll
            for (int dx = 0; dx < 3; ++dx)
                iv[dy * 3 + dx] = s_img[yy + dy][xx + dx];
#pragma unroll
        for (int co = 0; co < 16; ++co) {
            float a = s_b1[co];
#pragma unroll
            for (int k = 0; k < 9; ++k) a = fmaf(iv[k], s_w1[co * 9 + k], a);
            s_c1[co][yy][xx] = inb ? fmaxf(a, 0.0f) : 0.0f;
        }
    }
    __syncthreads();
    int pg = t & 63;
    int cog = t >> 6;
    int ry = pg >> 2;
    int rx = (pg & 3) * 8;
    float acc[8][8];
#pragma unroll
    for (int i = 0; i < 8; ++i)
#pragma unroll
        for (int j = 0; j < 8; ++j) acc[i][j] = 0.0f;
    for (int ci = 0; ci < 16; ++ci) {
        float in[3][10];
#pragma unroll
        for (int dy = 0; dy < 3; ++dy)
#pragma unroll
            for (int xx = 0; xx < 10; ++xx)
                in[dy][xx] = s_c1[ci][ry + dy][rx + xx];
#pragma unroll
        for (int coi = 0; coi < 8; ++coi) {
            const float* wp = &s_w2[(cog * 8 + coi) * 144 + ci * 9];
            float w0 = wp[0], w1v = wp[1], w2v = wp[2], w3 = wp[3], w4 = wp[4],
                  w5 = wp[5], w6 = wp[6], w7 = wp[7], w8 = wp[8];
#pragma unroll
            for (int px = 0; px < 8; ++px) {
                float a = acc[coi][px];
                a = fmaf(in[0][px],     w0,  a);
                a = fmaf(in[0][px + 1], w1v, a);
                a = fmaf(in[0][px + 2], w2v, a);
                a = fmaf(in[1][px],     w3,  a);
                a = fmaf(in[1][px + 1], w4,  a);
                a = fmaf(in[1][px + 2], w5,  a);
                a = fmaf(in[2][px],     w6,  a);
                a = fmaf(in[2][px + 1], w7,  a);
                a = fmaf(in[2][px + 2], w8,  a);
                acc[coi][px] = a;
            }
        }
    }
    int y = by * 16 + ry;
    if (y < G) {
#pragma unroll
        for (int coi = 0; coi < 8; ++coi) {
            int co = cog * 8 + coi;
            float bv = b2[co];
#pragma unroll
            for (int px = 0; px < 8; ++px) {
                int x = bx * 32 + rx + px;
                if (x < G)
                    h[((size_t)(b * 32 + co)) * GG + y * G + x] =
                        fmaxf(acc[coi][px] + bv, 0.0f);
            }
        }
    }
}

// ---------------- fc1: skinny GEMM, all 64 rows per block, reg double-buffer --
// 512 thr = 8 waves; wave w = row-group g=w (rows 8w..8w+7) x 8 batches.
// Block s covers chunks [s*SPAN, s*SPAN+SPAN). h chunk fetched once per span
// (8 waves share via L1/L2). Ping-pong register prefetch: chunk c+1's 16 loads
// are in flight while chunk c's 256 FMAs run. No LDS, no barriers.
#define LOADCH(WV, HV, c)                                                       \
    {                                                                           \
        int j = (c) * 256 + l * 4;                                              \
        _Pragma("unroll")                                                       \
        for (int oi = 0; oi < 8; ++oi)                                          \
            WV[oi] = *(const float4*)(wrow[oi] + j);                            \
        bool ok = j < HFEAT;                                                    \
        _Pragma("unroll")                                                       \
        for (int b = 0; b < 8; ++b)                                             \
            HV[b] = ok ? *(const float4*)(h + (size_t)b * HFEAT + j) : f4z;     \
    }

#define FMACH(WV, HV)                                                           \
    {                                                                           \
        _Pragma("unroll")                                                       \
        for (int oi = 0; oi < 8; ++oi) {                                        \
            _Pragma("unroll")                                                   \
            for (int b = 0; b < 8; ++b) {                                       \
                float a = acc[oi * 8 + b];                                      \
                a = fmaf(WV[oi].x, HV[b].x, a);                                 \
                a = fmaf(WV[oi].y, HV[b].y, a);                                 \
                a = fmaf(WV[oi].z, HV[b].z, a);                                 \
                a = fmaf(WV[oi].w, HV[b].w, a);                                 \
                acc[oi * 8 + b] = a;                                            \
            }                                                                   \
        }                                                                       \
    }

__global__ __launch_bounds__(512, 2) void k_fc1(const float* __restrict__ h,
                                                const float* __restrict__ W1,
                                                float* __restrict__ accout) {
    int t = threadIdx.x;
    int g = t >> 6;                 // wave = row-group, rows 8g..8g+7
    int l = t & 63;
    int cbeg = blockIdx.x * SPAN;
    if (cbeg >= NCH) return;
    int cend = min(cbeg + SPAN, NCH);

    const float* wrow[8];
#pragma unroll
    for (int oi = 0; oi < 8; ++oi)
        wrow[oi] = W1 + (size_t)(g * 8 + oi) * W1STRIDE;

    float acc[64];
#pragma unroll
    for (int i = 0; i < 64; ++i) acc[i] = 0.0f;

    const float4 f4z = make_float4(0.f, 0.f, 0.f, 0.f);
    float4 wa[8], ha[8], wb[8], hb[8];

    LOADCH(wa, ha, cbeg)
    int c = cbeg;
    for (; c + 2 <= cend; c += 2) {
        LOADCH(wb, hb, c + 1)
        FMACH(wa, ha)
        if (c + 2 < cend) LOADCH(wa, ha, c + 2)
        FMACH(wb, hb)
    }
    if (c < cend) FMACH(wa, ha)     // odd tail (cend-cbeg odd)

    // transposing butterfly: lane l ends with full sum of value brev6(l)
    int cnt = 64;
#pragma unroll
    for (int st = 0; st < 6; ++st) {
        int half = cnt >> 1;
        bool up = (l >> st) & 1;
#pragma unroll
        for (int i = 0; i < half; ++i) {
            float send = up ? acc[i] : acc[i + half];
            float keep = up ? acc[i + half] : acc[i];
            float recv = __shfl_xor(send, 1 << st, 64);
            acc[i] = keep + recv;
        }
        cnt = half;
    }
    unsigned vi = __brev((unsigned)l) >> 26;   // value index = oi*8 + b
    atomicAdd(&accout[g * 64 + vi], acc[0]);   // accout layout [o][b]
}

// ---------------- finalize: wind MLP + fc1 tail + fc2 + fc3 ----------------
__global__ void k_final(const float* __restrict__ wind,
                        const float* __restrict__ ww1, const float* __restrict__ wb1,
                        const float* __restrict__ ww2, const float* __restrict__ wb2,
                        const float* __restrict__ ww3, const float* __restrict__ wb3,
                        const float* __restrict__ W1, const float* __restrict__ fb1,
                        const float* __restrict__ acc,
                        const float* __restrict__ w2, const float* __restrict__ b2,
                        const float* __restrict__ w3, const float* __restrict__ b3,
                        float* __restrict__ out) {
    __shared__ float s1[8][64], s2[8][64], f1[8][64], f2[8][32];
    int t = threadIdx.x;
    if (t < 64) {
        for (int b = 0; b < 8; ++b) {
            float v = wb1[t] + ww1[t * 2] * wind[b * 2] + ww1[t * 2 + 1] * wind[b * 2 + 1];
            s1[b][t] = fmaxf(v, 0.0f);
        }
    }
    __syncthreads();
    if (t < 64) {
        for (int b = 0; b < 8; ++b) {
            float v = wb2[t];
            for (int k = 0; k < 64; ++k) v = fmaf(s1[b][k], ww2[t * 64 + k], v);
            s2[b][t] = fmaxf(v, 0.0f);
        }
    }
    __syncthreads();
    if (t < 64) {
        for (int b = 0; b < 8; ++b) {
            float v = wb3[t];
            for (int k = 0; k < 64; ++k) v = fmaf(s2[b][k], ww3[t * 64 + k], v);
            s1[b][t] = fmaxf(v, 0.0f);   // reuse s1 = wind output
        }
    }
    __syncthreads();
    if (t < 64) {
        for (int b = 0; b < 8; ++b) {
            float v = fb1[t] + acc[t * 8 + b];
            const float* wrow = W1 + (size_t)t * W1STRIDE + HFEAT;
            for (int k = 0; k < 64; ++k) v = fmaf(s1[b][k], wrow[k], v);
            f1[b][t] = fmaxf(v, 0.0f);
        }
    }
    __syncthreads();
    if (t < 32) {
        for (int b = 0; b < 8; ++b) {
            float v = b2[t];
            for (int k = 0; k < 64; ++k) v = fmaf(f1[b][k], w2[t * 64 + k], v);
            f2[b][t] = fmaxf(v, 0.0f);
        }
    }
    __syncthreads();
    if (t < 200) {
        for (int b = 0; b < 8; ++b) {
            float v = b3[t];
            for (int k = 0; k < 32; ++k) v = fmaf(f2[b][k], w3[t * 32 + k], v);
            out[b * 200 + t] = v;
        }
    }
}

extern "C" void kernel_launch(void* const* d_in, const int* in_sizes, int n_in,
                              void* d_out, int out_size, void* d_ws, size_t ws_size,
                              hipStream_t stream) {
    const float* lidar = (const float*)d_in[0];
    const float* wind  = (const float*)d_in[1];
    const float* ww1 = (const float*)d_in[2];
    const float* wb1 = (const float*)d_in[3];
    const float* ww2 = (const float*)d_in[4];
    const float* wb2 = (const float*)d_in[5];
    const float* ww3 = (const float*)d_in[6];
    const float* wb3 = (const float*)d_in[7];
    const float* c1w = (const float*)d_in[8];
    const float* c1b = (const float*)d_in[9];
    const float* c2w = (const float*)d_in[10];
    const float* c2b = (const float*)d_in[11];
    const float* fw1 = (const float*)d_in[12];
    const float* fb1 = (const float*)d_in[13];
    const float* fw2 = (const float*)d_in[14];
    const float* fb2 = (const float*)d_in[15];
    const float* fw3 = (const float*)d_in[16];
    const float* fb3 = (const float*)d_in[17];
    float* out = (float*)d_out;

    // ws layout (floats): img 500,000 | h 16,000,000 | acc 512
    float* ws  = (float*)d_ws;
    float* img = ws;
    float* h   = ws + 500000;
    float* acc = ws + 16500000;

    hipMemsetAsync(img, 0, 500000 * sizeof(float), stream);
    hipMemsetAsync(acc, 0, 512 * sizeof(float), stream);

    k_raster<<<(NB * 360 * 1000 + 255) / 256, 256, 0, stream>>>(lidar, img);
    dim3 g2(8, 16, NB);
    k_conv12<<<g2, 256, 0, stream>>>(img, c1w, c1b, c2w, c2b, h);
    int nblk = (NCH + SPAN - 1) / SPAN;   // 489
    k_fc1<<<nblk, 512, 0, stream>>>(h, fw1, acc);
    k_final<<<1, 256, 0, stream>>>(wind, ww1, wb1, ww2, wb2, ww3, wb3,
                                   fw1, fb1, acc, fw2, fb2, fw3, fb3, out);
}

// Round 7
// 268.163 us; speedup vs baseline: 1.4724x; 1.4724x over previous
//
#include <hip/hip_runtime.h>

#define G 250
#define GG 62500
#define NB 8
#define HFEAT 2000000
#define W1STRIDE 2000064
#define SLAB 2048          // K floats per block
#define SLABF4 512         // float4 per batch per slab

// ---------------- rasterize ----------------
__global__ void k_raster(const float* __restrict__ lidar, float* __restrict__ img) {
    int idx = blockIdx.x * blockDim.x + threadIdx.x;
    if (idx >= NB * 360 * 1000) return;
    int k = idx % 1000;
    int ba = idx / 1000;
    int a = ba % 360;
    int b = ba / 360;
    float r = lidar[ba];
    if (!(r > 0.0f && r < 1.0f)) return;
    float tmr = __fsub_rn(2.0f, r);
    int n = (int)floorf(__fmul_rn(tmr, 500.0f)) + 1;
    if (k >= n) return;
    float denom = (float)(n - 1);
    const float delta = 6.2831855f / 359.0f;      // fp32, matches jnp.linspace step
    float angle = __fmul_rn((float)a, delta);
    float mag = __fadd_rn(r, __fdiv_rn(__fmul_rn((float)k, tmr), denom));
    float c = cosf(angle);
    float s = sinf(angle);
    float px = __fadd_rn(125.0f, __fmul_rn(__fmul_rn(mag, c), 100.0f));
    float py = __fadd_rn(125.0f, __fmul_rn(__fmul_rn(mag, s), 100.0f));
    int xg = (int)px;   // trunc toward zero
    int yg = (int)py;
    if (xg >= 0 && xg < G && yg >= 0 && yg < G)
        img[b * GG + yg * G + xg] = 1.0f;
}

// ---------------- fused conv1(1->16)+conv2(16->32) ----------------
__global__ __launch_bounds__(256) void k_conv12(const float* __restrict__ img,
                                                const float* __restrict__ w1,
                                                const float* __restrict__ b1,
                                                const float* __restrict__ w2,
                                                const float* __restrict__ b2,
                                                float* __restrict__ h) {
    __shared__ float s_img[20][37];
    __shared__ float s_c1[16][18][35];
    __shared__ float s_w2[4608];
    __shared__ float s_w1[144];
    __shared__ float s_b1[16];
    int t = threadIdx.x;
    int bx = blockIdx.x, by = blockIdx.y, b = blockIdx.z;
    for (int i = t; i < 4608; i += 256) s_w2[i] = w2[i];
    if (t < 144) s_w1[t] = w1[t];
    if (t < 16) s_b1[t] = b1[t];
    int x0 = bx * 32 - 1, y0 = by * 16 - 1;   // c1-tile origin
    for (int i = t; i < 20 * 36; i += 256) {
        int r = i / 36, c = i - r * 36;
        int gy = y0 - 1 + r, gx = x0 - 1 + c;
        float v = 0.0f;
        if (gy >= 0 && gy < G && gx >= 0 && gx < G) v = img[b * GG + gy * G + gx];
        s_img[r][c] = v;
    }
    __syncthreads();
    for (int i = t; i < 612; i += 256) {
        int yy = i / 34, xx = i - yy * 34;
        int gy = y0 + yy, gx = x0 + xx;
        bool inb = (gy >= 0 && gy < G && gx >= 0 && gx < G);
        float iv[9];
#pragma unroll
        for (int dy = 0; dy < 3; ++dy)
#pragma unroll
            for (int dx = 0; dx < 3; ++dx)
                iv[dy * 3 + dx] = s_img[yy + dy][xx + dx];
#pragma unroll
        for (int co = 0; co < 16; ++co) {
            float a = s_b1[co];
#pragma unroll
            for (int k = 0; k < 9; ++k) a = fmaf(iv[k], s_w1[co * 9 + k], a);
            s_c1[co][yy][xx] = inb ? fmaxf(a, 0.0f) : 0.0f;
        }
    }
    __syncthreads();
    int pg = t & 63;
    int cog = t >> 6;
    int ry = pg >> 2;
    int rx = (pg & 3) * 8;
    float acc[8][8];
#pragma unroll
    for (int i = 0; i < 8; ++i)
#pragma unroll
        for (int j = 0; j < 8; ++j) acc[i][j] = 0.0f;
    for (int ci = 0; ci < 16; ++ci) {
        float in[3][10];
#pragma unroll
        for (int dy = 0; dy < 3; ++dy)
#pragma unroll
            for (int xx = 0; xx < 10; ++xx)
                in[dy][xx] = s_c1[ci][ry + dy][rx + xx];
#pragma unroll
        for (int coi = 0; coi < 8; ++coi) {
            const float* wp = &s_w2[(cog * 8 + coi) * 144 + ci * 9];
            float w0 = wp[0], w1v = wp[1], w2v = wp[2], w3 = wp[3], w4 = wp[4],
                  w5 = wp[5], w6 = wp[6], w7 = wp[7], w8 = wp[8];
#pragma unroll
            for (int px = 0; px < 8; ++px) {
                float a = acc[coi][px];
                a = fmaf(in[0][px],     w0,  a);
                a = fmaf(in[0][px + 1], w1v, a);
                a = fmaf(in[0][px + 2], w2v, a);
                a = fmaf(in[1][px],     w3,  a);
                a = fmaf(in[1][px + 1], w4,  a);
                a = fmaf(in[1][px + 2], w5,  a);
                a = fmaf(in[2][px],     w6,  a);
                a = fmaf(in[2][px + 1], w7,  a);
                a = fmaf(in[2][px + 2], w8,  a);
                acc[coi][px] = a;
            }
        }
    }
    int y = by * 16 + ry;
    if (y < G) {
#pragma unroll
        for (int coi = 0; coi < 8; ++coi) {
            int co = cog * 8 + coi;
            float bv = b2[co];
#pragma unroll
            for (int px = 0; px < 8; ++px) {
                int x = bx * 32 + rx + px;
                if (x < G)
                    h[((size_t)(b * 32 + co)) * GG + y * G + x] =
                        fmaxf(acc[coi][px] + bv, 0.0f);
            }
        }
    }
}

// ---------------- fc1: one block = all 64 rows x one 2048-float K-slab -------
// 512 thr = 8 waves; wave w owns rows 8w..8w+7 x 8 batches (acc[64]/lane).
// h slab (8 batches x 2048 floats = 64 KB) staged in LDS once, ONE barrier.
// Compute: row-PAIRS outer, chunks inner -> each W-row stream is read as a
// sequential 8 KB burst (deep DRAM streams); h comes from LDS (no global
// re-reads). No spills: acc64 + hv32 + wv8 ~ 130 VGPR.
__global__ __launch_bounds__(512) void k_fc1(const float* __restrict__ h,
                                             const float* __restrict__ W1,
                                             float* __restrict__ accout) {
    __shared__ float4 s_h[8 * SLABF4];   // [batch][512 f4] = 64 KB
    int t = threadIdx.x;
    int w = t >> 6;                      // wave = row-group (rows 8w..8w+7)
    int l = t & 63;
    int j0 = blockIdx.x * SLAB;          // slab start (float index in K)
    const float4 f4z = make_float4(0.f, 0.f, 0.f, 0.f);

    // stage h slab: thread t stages f4 #t of each batch's slab (coalesced)
    {
        int j = j0 + t * 4;
        bool ok = j < HFEAT;
#pragma unroll
        for (int b = 0; b < 8; ++b) {
            float4 v = ok ? *(const float4*)(h + (size_t)b * HFEAT + j) : f4z;
            s_h[b * SLABF4 + t] = v;
        }
    }
    __syncthreads();

    float acc[64];
#pragma unroll
    for (int i = 0; i < 64; ++i) acc[i] = 0.0f;

    for (int p = 0; p < 4; ++p) {        // row pairs within the wave's 8 rows
        int r0 = w * 8 + 2 * p;
        const float* w0p = W1 + (size_t)r0 * W1STRIDE;
        const float* w1p = w0p + W1STRIDE;
#pragma unroll 2
        for (int c = 0; c < 8; ++c) {    // chunks: sequential 1 KB steps
            int j = j0 + c * 256 + l * 4;
            bool ok = j < HFEAT;
            float4 wv0 = ok ? *(const float4*)(w0p + j) : f4z;
            float4 wv1 = ok ? *(const float4*)(w1p + j) : f4z;
            float4 hv[8];
#pragma unroll
            for (int b = 0; b < 8; ++b)
                hv[b] = s_h[b * SLABF4 + c * 64 + l];
#pragma unroll
            for (int b = 0; b < 8; ++b) {
                float a0 = acc[(2 * p) * 8 + b];
                float a1 = acc[(2 * p + 1) * 8 + b];
                a0 = fmaf(wv0.x, hv[b].x, a0);
                a0 = fmaf(wv0.y, hv[b].y, a0);
                a0 = fmaf(wv0.z, hv[b].z, a0);
                a0 = fmaf(wv0.w, hv[b].w, a0);
                a1 = fmaf(wv1.x, hv[b].x, a1);
                a1 = fmaf(wv1.y, hv[b].y, a1);
                a1 = fmaf(wv1.z, hv[b].z, a1);
                a1 = fmaf(wv1.w, hv[b].w, a1);
                acc[(2 * p) * 8 + b] = a0;
                acc[(2 * p + 1) * 8 + b] = a1;
            }
        }
    }

    // transposing butterfly: lane l ends with full sum of value brev6(l)
    int cnt = 64;
#pragma unroll
    for (int st = 0; st < 6; ++st) {
        int half = cnt >> 1;
        bool up = (l >> st) & 1;
#pragma unroll
        for (int i = 0; i < half; ++i) {
            float send = up ? acc[i] : acc[i + half];
            float keep = up ? acc[i + half] : acc[i];
            float recv = __shfl_xor(send, 1 << st, 64);
            acc[i] = keep + recv;
        }
        cnt = half;
    }
    unsigned vi = __brev((unsigned)l) >> 26;   // value index = oi*8 + b
    atomicAdd(&accout[w * 64 + vi], acc[0]);   // accout layout [o][b]
}

// ---------------- finalize: wind MLP + fc1 tail + fc2 + fc3 ----------------
__global__ void k_final(const float* __restrict__ wind,
                        const float* __restrict__ ww1, const float* __restrict__ wb1,
                        const float* __restrict__ ww2, const float* __restrict__ wb2,
                        const float* __restrict__ ww3, const float* __restrict__ wb3,
                        const float* __restrict__ W1, const float* __restrict__ fb1,
                        const float* __restrict__ acc,
                        const float* __restrict__ w2, const float* __restrict__ b2,
                        const float* __restrict__ w3, const float* __restrict__ b3,
                        float* __restrict__ out) {
    __shared__ float s1[8][64], s2[8][64], f1[8][64], f2[8][32];
    int t = threadIdx.x;
    if (t < 64) {
        for (int b = 0; b < 8; ++b) {
            float v = wb1[t] + ww1[t * 2] * wind[b * 2] + ww1[t * 2 + 1] * wind[b * 2 + 1];
            s1[b][t] = fmaxf(v, 0.0f);
        }
    }
    __syncthreads();
    if (t < 64) {
        for (int b = 0; b < 8; ++b) {
            float v = wb2[t];
            for (int k = 0; k < 64; ++k) v = fmaf(s1[b][k], ww2[t * 64 + k], v);
            s2[b][t] = fmaxf(v, 0.0f);
        }
    }
    __syncthreads();
    if (t < 64) {
        for (int b = 0; b < 8; ++b) {
            float v = wb3[t];
            for (int k = 0; k < 64; ++k) v = fmaf(s2[b][k], ww3[t * 64 + k], v);
            s1[b][t] = fmaxf(v, 0.0f);   // reuse s1 = wind output
        }
    }
    __syncthreads();
    if (t < 64) {
        for (int b = 0; b < 8; ++b) {
            float v = fb1[t] + acc[t * 8 + b];
            const float* wrow = W1 + (size_t)t * W1STRIDE + HFEAT;
            for (int k = 0; k < 64; ++k) v = fmaf(s1[b][k], wrow[k], v);
            f1[b][t] = fmaxf(v, 0.0f);
        }
    }
    __syncthreads();
    if (t < 32) {
        for (int b = 0; b < 8; ++b) {
            float v = b2[t];
            for (int k = 0; k < 64; ++k) v = fmaf(f1[b][k], w2[t * 64 + k], v);
            f2[b][t] = fmaxf(v, 0.0f);
        }
    }
    __syncthreads();
    if (t < 200) {
        for (int b = 0; b < 8; ++b) {
            float v = b3[t];
            for (int k = 0; k < 32; ++k) v = fmaf(f2[b][k], w3[t * 32 + k], v);
            out[b * 200 + t] = v;
        }
    }
}

extern "C" void kernel_launch(void* const* d_in, const int* in_sizes, int n_in,
                              void* d_out, int out_size, void* d_ws, size_t ws_size,
                              hipStream_t stream) {
    const float* lidar = (const float*)d_in[0];
    const float* wind  = (const float*)d_in[1];
    const float* ww1 = (const float*)d_in[2];
    const float* wb1 = (const float*)d_in[3];
    const float* ww2 = (const float*)d_in[4];
    const float* wb2 = (const float*)d_in[5];
    const float* ww3 = (const float*)d_in[6];
    const float* wb3 = (const float*)d_in[7];
    const float* c1w = (const float*)d_in[8];
    const float* c1b = (const float*)d_in[9];
    const float* c2w = (const float*)d_in[10];
    const float* c2b = (const float*)d_in[11];
    const float* fw1 = (const float*)d_in[12];
    const float* fb1 = (const float*)d_in[13];
    const float* fw2 = (const float*)d_in[14];
    const float* fb2 = (const float*)d_in[15];
    const float* fw3 = (const float*)d_in[16];
    const float* fb3 = (const float*)d_in[17];
    float* out = (float*)d_out;

    // ws layout (floats): img 500,000 | h 16,000,000 | acc 512
    float* ws  = (float*)d_ws;
    float* img = ws;
    float* h   = ws + 500000;
    float* acc = ws + 16500000;

    hipMemsetAsync(img, 0, 500000 * sizeof(float), stream);
    hipMemsetAsync(acc, 0, 512 * sizeof(float), stream);

    k_raster<<<(NB * 360 * 1000 + 255) / 256, 256, 0, stream>>>(lidar, img);
    dim3 g2(8, 16, NB);
    k_conv12<<<g2, 256, 0, stream>>>(img, c1w, c1b, c2w, c2b, h);
    int nblk = (HFEAT + SLAB - 1) / SLAB;   // 977
    k_fc1<<<nblk, 512, 0, stream>>>(h, fw1, acc);
    k_final<<<1, 256, 0, stream>>>(wind, ww1, wb1, ww2, wb2, ww3, wb3,
                                   fw1, fb1, acc, fw2, fb2, fw3, fb3, out);
}

// Round 8
// 233.281 us; speedup vs baseline: 1.6926x; 1.1495x over previous
//
#include <hip/hip_runtime.h>

#define G 250
#define GG 62500
#define NB 8
#define HFEAT 2000000
#define W1STRIDE 2000064
#define NCH 7813          // ceil(2,000,000 / 256)
#define SPAN 8            // chunks per block-pair (contiguous)

typedef float f4v __attribute__((ext_vector_type(4)));

// ---------------- rasterize ----------------
__global__ void k_raster(const float* __restrict__ lidar, float* __restrict__ img) {
    int idx = blockIdx.x * blockDim.x + threadIdx.x;
    if (idx >= NB * 360 * 1000) return;
    int k = idx % 1000;
    int ba = idx / 1000;
    int a = ba % 360;
    int b = ba / 360;
    float r = lidar[ba];
    if (!(r > 0.0f && r < 1.0f)) return;
    float tmr = __fsub_rn(2.0f, r);
    int n = (int)floorf(__fmul_rn(tmr, 500.0f)) + 1;
    if (k >= n) return;
    float denom = (float)(n - 1);
    const float delta = 6.2831855f / 359.0f;      // fp32, matches jnp.linspace step
    float angle = __fmul_rn((float)a, delta);
    float mag = __fadd_rn(r, __fdiv_rn(__fmul_rn((float)k, tmr), denom));
    float c = cosf(angle);
    float s = sinf(angle);
    float px = __fadd_rn(125.0f, __fmul_rn(__fmul_rn(mag, c), 100.0f));
    float py = __fadd_rn(125.0f, __fmul_rn(__fmul_rn(mag, s), 100.0f));
    int xg = (int)px;   // trunc toward zero
    int yg = (int)py;
    if (xg >= 0 && xg < G && yg >= 0 && yg < G)
        img[b * GG + yg * G + xg] = 1.0f;
}

// ---------------- fused conv1(1->16)+conv2(16->32) ----------------
__global__ __launch_bounds__(256) void k_conv12(const float* __restrict__ img,
                                                const float* __restrict__ w1,
                                                const float* __restrict__ b1,
                                                const float* __restrict__ w2,
                                                const float* __restrict__ b2,
                                                float* __restrict__ h) {
    __shared__ float s_img[20][37];
    __shared__ float s_c1[16][18][35];
    __shared__ float s_w2[4608];
    __shared__ float s_w1[144];
    __shared__ float s_b1[16];
    int t = threadIdx.x;
    int bx = blockIdx.x, by = blockIdx.y, b = blockIdx.z;
    for (int i = t; i < 4608; i += 256) s_w2[i] = w2[i];
    if (t < 144) s_w1[t] = w1[t];
    if (t < 16) s_b1[t] = b1[t];
    int x0 = bx * 32 - 1, y0 = by * 16 - 1;   // c1-tile origin
    for (int i = t; i < 20 * 36; i += 256) {
        int r = i / 36, c = i - r * 36;
        int gy = y0 - 1 + r, gx = x0 - 1 + c;
        float v = 0.0f;
        if (gy >= 0 && gy < G && gx >= 0 && gx < G) v = img[b * GG + gy * G + gx];
        s_img[r][c] = v;
    }
    __syncthreads();
    for (int i = t; i < 612; i += 256) {
        int yy = i / 34, xx = i - yy * 34;
        int gy = y0 + yy, gx = x0 + xx;
        bool inb = (gy >= 0 && gy < G && gx >= 0 && gx < G);
        float iv[9];
#pragma unroll
        for (int dy = 0; dy < 3; ++dy)
#pragma unroll
            for (int dx = 0; dx < 3; ++dx)
                iv[dy * 3 + dx] = s_img[yy + dy][xx + dx];
#pragma unroll
        for (int co = 0; co < 16; ++co) {
            float a = s_b1[co];
#pragma unroll
            for (int k = 0; k < 9; ++k) a = fmaf(iv[k], s_w1[co * 9 + k], a);
            s_c1[co][yy][xx] = inb ? fmaxf(a, 0.0f) : 0.0f;
        }
    }
    __syncthreads();
    int pg = t & 63;
    int cog = t >> 6;
    int ry = pg >> 2;
    int rx = (pg & 3) * 8;
    float acc[8][8];
#pragma unroll
    for (int i = 0; i < 8; ++i)
#pragma unroll
        for (int j = 0; j < 8; ++j) acc[i][j] = 0.0f;
    for (int ci = 0; ci < 16; ++ci) {
        float in[3][10];
#pragma unroll
        for (int dy = 0; dy < 3; ++dy)
#pragma unroll
            for (int xx = 0; xx < 10; ++xx)
                in[dy][xx] = s_c1[ci][ry + dy][rx + xx];
#pragma unroll
        for (int coi = 0; coi < 8; ++coi) {
            const float* wp = &s_w2[(cog * 8 + coi) * 144 + ci * 9];
            float w0 = wp[0], w1v = wp[1], w2v = wp[2], w3 = wp[3], w4 = wp[4],
                  w5 = wp[5], w6 = wp[6], w7 = wp[7], w8 = wp[8];
#pragma unroll
            for (int px = 0; px < 8; ++px) {
                float a = acc[coi][px];
                a = fmaf(in[0][px],     w0,  a);
                a = fmaf(in[0][px + 1], w1v, a);
                a = fmaf(in[0][px + 2], w2v, a);
                a = fmaf(in[1][px],     w3,  a);
                a = fmaf(in[1][px + 1], w4,  a);
                a = fmaf(in[1][px + 2], w5,  a);
                a = fmaf(in[2][px],     w6,  a);
                a = fmaf(in[2][px + 1], w7,  a);
                a = fmaf(in[2][px + 2], w8,  a);
                acc[coi][px] = a;
            }
        }
    }
    int y = by * 16 + ry;
    if (y < G) {
#pragma unroll
        for (int coi = 0; coi < 8; ++coi) {
            int co = cog * 8 + coi;
            float bv = b2[co];
#pragma unroll
            for (int px = 0; px < 8; ++px) {
                int x = bx * 32 + rx + px;
                if (x < G)
                    h[((size_t)(b * 32 + co)) * GG + y * G + x] =
                        fmaxf(acc[coi][px] + bv, 0.0f);
            }
        }
    }
}

// ---------------- fc1: barrier-free skinny GEMM (R4 structure) ----------------
// 256 thr = 4 waves. Block pair (2s, 2s+1) covers all 64 rows over chunk span
// [s*SPAN, s*SPAN+SPAN): wave w of block handles row-group g = w + 4*(blk&1).
// The 4 waves of a block read the SAME h chunks (L1/L2/L3 hits); W rows stream
// contiguous spans per block with NON-TEMPORAL loads (read-once; don't evict h).
__global__ __launch_bounds__(256) void k_fc1(const float* __restrict__ h,
                                             const float* __restrict__ W1,
                                             float* __restrict__ accout) {
    int t = threadIdx.x;
    int w = t >> 6;
    int l = t & 63;
    int s = blockIdx.x >> 1;
    int g = ((blockIdx.x & 1) << 2) | w;   // 0..7 -> rows 8g..8g+7
    int cbeg = s * SPAN;
    if (cbeg >= NCH) return;
    int cend = min(cbeg + SPAN, NCH);

    const float* wrow[8];
#pragma unroll
    for (int oi = 0; oi < 8; ++oi)
        wrow[oi] = W1 + (size_t)(g * 8 + oi) * W1STRIDE;

    float acc[64];
#pragma unroll
    for (int i = 0; i < 64; ++i) acc[i] = 0.0f;

    for (int c = cbeg; c < cend; ++c) {
        int j = c * 256 + l * 4;
        if (j < HFEAT) {
            f4v wv[8];
            float4 hv[8];
#pragma unroll
            for (int oi = 0; oi < 8; ++oi)
                wv[oi] = __builtin_nontemporal_load((const f4v*)(wrow[oi] + j));
#pragma unroll
            for (int b = 0; b < 8; ++b)
                hv[b] = *(const float4*)(h + (size_t)b * HFEAT + j);
#pragma unroll
            for (int oi = 0; oi < 8; ++oi) {
#pragma unroll
                for (int b = 0; b < 8; ++b) {
                    float a = acc[oi * 8 + b];
                    a = fmaf(wv[oi][0], hv[b].x, a);
                    a = fmaf(wv[oi][1], hv[b].y, a);
                    a = fmaf(wv[oi][2], hv[b].z, a);
                    a = fmaf(wv[oi][3], hv[b].w, a);
                    acc[oi * 8 + b] = a;
                }
            }
        }
    }

    // transposing butterfly: lane l ends with full sum of value brev6(l)
    int cnt = 64;
#pragma unroll
    for (int st = 0; st < 6; ++st) {
        int half = cnt >> 1;
        bool up = (l >> st) & 1;
#pragma unroll
        for (int i = 0; i < half; ++i) {
            float send = up ? acc[i] : acc[i + half];
            float keep = up ? acc[i + half] : acc[i];
            float recv = __shfl_xor(send, 1 << st, 64);
            acc[i] = keep + recv;
        }
        cnt = half;
    }
    unsigned vi = __brev((unsigned)l) >> 26;   // value index = oi*8 + b
    atomicAdd(&accout[g * 64 + vi], acc[0]);   // accout layout [o][b]
}

// ---------------- finalize: wind MLP + fc1 tail + fc2 + fc3 ----------------
__global__ void k_final(const float* __restrict__ wind,
                        const float* __restrict__ ww1, const float* __restrict__ wb1,
                        const float* __restrict__ ww2, const float* __restrict__ wb2,
                        const float* __restrict__ ww3, const float* __restrict__ wb3,
                        const float* __restrict__ W1, const float* __restrict__ fb1,
                        const float* __restrict__ acc,
                        const float* __restrict__ w2, const float* __restrict__ b2,
                        const float* __restrict__ w3, const float* __restrict__ b3,
                        float* __restrict__ out) {
    __shared__ float s1[8][64], s2[8][64], f1[8][64], f2[8][32];
    int t = threadIdx.x;
    if (t < 64) {
        for (int b = 0; b < 8; ++b) {
            float v = wb1[t] + ww1[t * 2] * wind[b * 2] + ww1[t * 2 + 1] * wind[b * 2 + 1];
            s1[b][t] = fmaxf(v, 0.0f);
        }
    }
    __syncthreads();
    if (t < 64) {
        for (int b = 0; b < 8; ++b) {
            float v = wb2[t];
            for (int k = 0; k < 64; ++k) v = fmaf(s1[b][k], ww2[t * 64 + k], v);
            s2[b][t] = fmaxf(v, 0.0f);
        }
    }
    __syncthreads();
    if (t < 64) {
        for (int b = 0; b < 8; ++b) {
            float v = wb3[t];
            for (int k = 0; k < 64; ++k) v = fmaf(s2[b][k], ww3[t * 64 + k], v);
            s1[b][t] = fmaxf(v, 0.0f);   // reuse s1 = wind output
        }
    }
    __syncthreads();
    if (t < 64) {
        for (int b = 0; b < 8; ++b) {
            float v = fb1[t] + acc[t * 8 + b];
            const float* wrow = W1 + (size_t)t * W1STRIDE + HFEAT;
            for (int k = 0; k < 64; ++k) v = fmaf(s1[b][k], wrow[k], v);
            f1[b][t] = fmaxf(v, 0.0f);
        }
    }
    __syncthreads();
    if (t < 32) {
        for (int b = 0; b < 8; ++b) {
            float v = b2[t];
            for (int k = 0; k < 64; ++k) v = fmaf(f1[b][k], w2[t * 64 + k], v);
            f2[b][t] = fmaxf(v, 0.0f);
        }
    }
    __syncthreads();
    if (t < 200) {
        for (int b = 0; b < 8; ++b) {
            float v = b3[t];
            for (int k = 0; k < 32; ++k) v = fmaf(f2[b][k], w3[t * 32 + k], v);
            out[b * 200 + t] = v;
        }
    }
}

extern "C" void kernel_launch(void* const* d_in, const int* in_sizes, int n_in,
                              void* d_out, int out_size, void* d_ws, size_t ws_size,
                              hipStream_t stream) {
    const float* lidar = (const float*)d_in[0];
    const float* wind  = (const float*)d_in[1];
    const float* ww1 = (const float*)d_in[2];
    const float* wb1 = (const float*)d_in[3];
    const float* ww2 = (const float*)d_in[4];
    const float* wb2 = (const float*)d_in[5];
    const float* ww3 = (const float*)d_in[6];
    const float* wb3 = (const float*)d_in[7];
    const float* c1w = (const float*)d_in[8];
    const float* c1b = (const float*)d_in[9];
    const float* c2w = (const float*)d_in[10];
    const float* c2b = (const float*)d_in[11];
    const float* fw1 = (const float*)d_in[12];
    const float* fb1 = (const float*)d_in[13];
    const float* fw2 = (const float*)d_in[14];
    const float* fb2 = (const float*)d_in[15];
    const float* fw3 = (const float*)d_in[16];
    const float* fb3 = (const float*)d_in[17];
    float* out = (float*)d_out;

    // ws layout (floats): img 500,000 | h 16,000,000 | acc 512
    float* ws  = (float*)d_ws;
    float* img = ws;
    float* h   = ws + 500000;
    float* acc = ws + 16500000;

    hipMemsetAsync(img, 0, 500000 * sizeof(float), stream);
    hipMemsetAsync(acc, 0, 512 * sizeof(float), stream);

    k_raster<<<(NB * 360 * 1000 + 255) / 256, 256, 0, stream>>>(lidar, img);
    dim3 g2(8, 16, NB);
    k_conv12<<<g2, 256, 0, stream>>>(img, c1w, c1b, c2w, c2b, h);
    int nblk = 2 * ((NCH + SPAN - 1) / SPAN);   // 1954
    k_fc1<<<nblk, 256, 0, stream>>>(h, fw1, acc);
    k_final<<<1, 256, 0, stream>>>(wind, ww1, wb1, ww2, wb2, ww3, wb3,
                                   fw1, fb1, acc, fw2, fb2, fw3, fb3, out);
}